// Round 1
// baseline (707.182 us; speedup 1.0000x reference)
//
#include <hip/hip_runtime.h>

#define NN 4096
#define CCH 128

// ---------------------------------------------------------------- kernel 0
__global__ __launch_bounds__(256) void transpose_w(
    const float* __restrict__ wq, const float* __restrict__ wk, const float* __restrict__ wv,
    const float* __restrict__ w1,
    float* __restrict__ wTq, float* __restrict__ wTk, float* __restrict__ wTv,
    float* __restrict__ w1T) {
  int t = blockIdx.x * 256 + threadIdx.x;
  if (t < 64 * 262) {
    int o = t / 262, c = t - o * 262;
    wTq[c * 64 + o] = wq[t];
    wTk[c * 64 + o] = wk[t];
    wTv[c * 64 + o] = wv[t];
  }
  if (t < 128 * 64) {
    int r = t >> 6, c2 = t & 63;
    w1T[c2 * 128 + r] = w1[t];  // w1T[o][c]
  }
}

// ---------------------------------------------------------------- kernel 1: kNN
// Block: 256 threads = 64 queries x 4 candidate-chunks. LDS: all 4096 points (x,y,z,|x|^2).
__global__ __launch_bounds__(256) void knn_kernel(const float* __restrict__ xyz,
                                                  int* __restrict__ idxout) {
  __shared__ float4 pts[NN];  // 64 KB; re-used as merge scratch afterwards
  const int b  = blockIdx.x >> 6;
  const int n0 = (blockIdx.x & 63) << 6;
  const float* xb = xyz + (size_t)b * 3 * NN;
  for (int i = threadIdx.x; i < NN; i += 256) {
    float x = xb[i], y = xb[NN + i], z = xb[2 * NN + i];
    pts[i] = make_float4(x, y, z, x * x + y * y + z * z);
  }
  __syncthreads();
  const int ql = threadIdx.x & 63;
  const int chunk = threadIdx.x >> 6;
  const int q = n0 + ql;
  const float4 me = pts[q];
  float bd[16];
  int bi[16];
#pragma unroll
  for (int j = 0; j < 16; ++j) { bd[j] = 3.0e38f; bi[j] = 0; }
  const int mend = (chunk + 1) << 10;
  for (int m = chunk << 10; m < mend; ++m) {
    float4 p = pts[m];
    float d = me.w + p.w - 2.0f * (me.x * p.x + me.y * p.y + me.z * p.z);
    if (d < bd[15] && m != q) {   // self-distance is exactly 0 -> excluded like ref's drop-first
#pragma unroll
      for (int j = 15; j > 0; --j) {
        bool up   = d < bd[j - 1];
        bool here = d < bd[j];
        bd[j] = up ? bd[j - 1] : (here ? d : bd[j]);
        bi[j] = up ? bi[j - 1] : (here ? m : bi[j]);
      }
      if (d < bd[0]) { bd[0] = d; bi[0] = m; }
    }
  }
  __syncthreads();
  // merge scratch aliased onto pts: per query: 4 chunks x 16 entries, stride 68 (bank spread)
  float* sd = reinterpret_cast<float*>(pts);
  int*   si = reinterpret_cast<int*>(sd + 64 * 68);
  {
    const int basep = ql * 68 + chunk * 16;
#pragma unroll
    for (int j = 0; j < 16; ++j) { sd[basep + j] = bd[j]; si[basep + j] = bi[j]; }
  }
  __syncthreads();
  if (threadIdx.x < 64) {
    const int qb = threadIdx.x * 68;
    int p0 = 0, p1 = 0, p2 = 0, p3 = 0;
    int* op = idxout + ((size_t)((b << 12) + n0 + threadIdx.x)) * 16;
    for (int k = 0; k < 16; ++k) {
      float v0 = sd[qb + p0], v1 = sd[qb + 16 + p1], v2 = sd[qb + 32 + p2], v3 = sd[qb + 48 + p3];
      float bv = v0; int c = 0;
      if (v1 < bv) { bv = v1; c = 1; }   // strict <: lower chunk (= lower index) wins ties
      if (v2 < bv) { bv = v2; c = 2; }
      if (v3 < bv) { bv = v3; c = 3; }
      int sel;
      if (c == 0)      { sel = si[qb + p0];      ++p0; }
      else if (c == 1) { sel = si[qb + 16 + p1]; ++p1; }
      else if (c == 2) { sel = si[qb + 32 + p2]; ++p2; }
      else             { sel = si[qb + 48 + p3]; ++p3; }
      op[k] = sel;
    }
  }
}

// ---------------------------------------------------------------- kernel 2: projections
// u[p] = W_rx*x + W_rf*f ; c[p] = (W_x*x + W_f*f + b) - u[p]   for q,k,v
__global__ __launch_bounds__(256) void proj_kernel(
    const float* __restrict__ feature, const float* __restrict__ xyz,
    const float* __restrict__ wTq, const float* __restrict__ wTk, const float* __restrict__ wTv,
    const float* __restrict__ bq, const float* __restrict__ bk, const float* __restrict__ bv,
    float* __restrict__ uq, float* __restrict__ cq,
    float* __restrict__ uk, float* __restrict__ ck,
    float* __restrict__ uv, float* __restrict__ cv) {
  __shared__ float fl[64][132];  // [point][128 fea + x,y,z + pad]
  const int b  = blockIdx.x >> 6;
  const int n0 = (blockIdx.x & 63) << 6;
  {
    const int i  = threadIdx.x & 63;
    const int c0 = threadIdx.x >> 6;
    const float* fb = feature + (size_t)b * CCH * NN + n0 + i;
    for (int cc = c0; cc < CCH; cc += 4) fl[i][cc] = fb[(size_t)cc * NN];
    if (threadIdx.x < 192) {
      const int d = threadIdx.x >> 6;  // 0..2
      fl[i][128 + d] = xyz[((size_t)b * 3 + d) * NN + n0 + i];
    }
  }
  __syncthreads();
  const int o  = threadIdx.x & 63;
  const int pg = threadIdx.x >> 6;
  const float* wt0 = wTq; const float* wt1 = wTk; const float* wt2 = wTv;
  float aU[3][16], aT[3][16];
#pragma unroll
  for (int mm = 0; mm < 3; ++mm)
#pragma unroll
    for (int s = 0; s < 16; ++s) { aU[mm][s] = 0.f; aT[mm][s] = 0.f; }
  for (int ct = 0; ct < 32; ++ct) {
    float wu[3][4], wtt[3][4];
#pragma unroll
    for (int r = 0; r < 4; ++r) {
      int c = 4 * ct + r;
      wu[0][r]  = wt0[(6 + c) * 64 + o];   wtt[0][r] = wt0[(134 + c) * 64 + o];
      wu[1][r]  = wt1[(6 + c) * 64 + o];   wtt[1][r] = wt1[(134 + c) * 64 + o];
      wu[2][r]  = wt2[(6 + c) * 64 + o];   wtt[2][r] = wt2[(134 + c) * 64 + o];
    }
#pragma unroll
    for (int s = 0; s < 16; ++s) {
      const float4 f4 = *reinterpret_cast<const float4*>(&fl[pg * 16 + s][4 * ct]);
#pragma unroll
      for (int mm = 0; mm < 3; ++mm) {
        aU[mm][s] += wu[mm][0] * f4.x + wu[mm][1] * f4.y + wu[mm][2] * f4.z + wu[mm][3] * f4.w;
        aT[mm][s] += wtt[mm][0] * f4.x + wtt[mm][1] * f4.y + wtt[mm][2] * f4.z + wtt[mm][3] * f4.w;
      }
    }
  }
  float wxu[3][3], wxt[3][3];
#pragma unroll
  for (int dd = 0; dd < 3; ++dd) {
    wxu[0][dd] = wt0[dd * 64 + o]; wxt[0][dd] = wt0[(3 + dd) * 64 + o];
    wxu[1][dd] = wt1[dd * 64 + o]; wxt[1][dd] = wt1[(3 + dd) * 64 + o];
    wxu[2][dd] = wt2[dd * 64 + o]; wxt[2][dd] = wt2[(3 + dd) * 64 + o];
  }
  const float bo0 = bq[o], bo1 = bk[o], bo2 = bv[o];
  for (int s = 0; s < 16; ++s) {
    const int p = pg * 16 + s;
    const float x = fl[p][128], y = fl[p][129], z = fl[p][130];
    const size_t gp = ((size_t)(b << 12) + n0 + p) * 64 + o;
    float uu, tt;
    uu = aU[0][s] + wxu[0][0] * x + wxu[0][1] * y + wxu[0][2] * z;
    tt = aT[0][s] + wxt[0][0] * x + wxt[0][1] * y + wxt[0][2] * z;
    uq[gp] = uu; cq[gp] = tt + bo0 - uu;
    uu = aU[1][s] + wxu[1][0] * x + wxu[1][1] * y + wxu[1][2] * z;
    tt = aT[1][s] + wxt[1][0] * x + wxt[1][1] * y + wxt[1][2] * z;
    uk[gp] = uu; ck[gp] = tt + bo1 - uu;
    uu = aU[2][s] + wxu[2][0] * x + wxu[2][1] * y + wxu[2][2] * z;
    tt = aT[2][s] + wxt[2][0] * x + wxt[2][1] * y + wxt[2][2] * z;
    uv[gp] = uu; cv[gp] = tt + bo2 - uu;
  }
}

// ---------------------------------------------------------------- kernel 3: attention + out
// One wave per point (lane = channel o of TD=64). 4 points per 256-thread block.
__global__ __launch_bounds__(256) void attn_kernel(
    const float* __restrict__ feature,
    const int* __restrict__ idx,
    const float* __restrict__ uq, const float* __restrict__ cq,
    const float* __restrict__ uk, const float* __restrict__ ck,
    const float* __restrict__ uv, const float* __restrict__ cv,
    const float* __restrict__ w1T, const float* __restrict__ b1,
    float* __restrict__ out) {
  __shared__ float kq[4][24][68];  // per wave-slot: rows 0..15 = k, 16..23 = q; stride 68
  const int slot = threadIdx.x >> 6;
  const int o    = threadIdx.x & 63;
  const int p = (blockIdx.x << 2) + slot;
  const int b = p >> 12;
  const int n = p & 4095;
  const int myidx = idx[(size_t)p * 16 + (o & 15)];
  const size_t pb = (size_t)p * 64 + o;
  const float cqo = cq[pb], cko = ck[pb], cvo = cv[pb];
  const int rowbase = (b << 12) * 64;
  float v[16];
#pragma unroll
  for (int j = 0; j < 16; ++j) {
    int nb = __shfl(myidx, j);
    int row = rowbase + nb * 64 + o;
    kq[slot][j][o] = uk[row] + cko;
    v[j] = uv[row] + cvo;
    if (j < 8) kq[slot][16 + j][o] = uq[row] + cqo;
  }
  // same-wave LDS write->read dependency: compiler inserts waitcnt, no barrier needed
  const int i  = o >> 3;   // query 0..7
  const int jj = o & 7;    // key (this lane covers jj and jj+8)
  const float* qrow = &kq[slot][16 + i][0];
  const float* k0r  = &kq[slot][jj][0];
  const float* k1r  = &kq[slot][8 + jj][0];
  float s0 = 0.f, s1 = 0.f;
#pragma unroll
  for (int t = 0; t < 16; ++t) {
    float4 q4 = *reinterpret_cast<const float4*>(qrow + 4 * t);
    float4 a4 = *reinterpret_cast<const float4*>(k0r + 4 * t);
    float4 c4 = *reinterpret_cast<const float4*>(k1r + 4 * t);
    s0 += q4.x * a4.x + q4.y * a4.y + q4.z * a4.z + q4.w * a4.w;
    s1 += q4.x * c4.x + q4.y * c4.y + q4.z * c4.z + q4.w * c4.w;
  }
  // softmax over 16 keys within each 8-lane query group
  float mx = fmaxf(s0, s1);
  mx = fmaxf(mx, __shfl_xor(mx, 1));
  mx = fmaxf(mx, __shfl_xor(mx, 2));
  mx = fmaxf(mx, __shfl_xor(mx, 4));
  float e0 = __expf(s0 - mx), e1 = __expf(s1 - mx);
  float den = e0 + e1;
  den += __shfl_xor(den, 1);
  den += __shfl_xor(den, 2);
  den += __shfl_xor(den, 4);
  const float inv = 1.0f / den;
  float w0 = e0 * inv, w1s = e1 * inv;
  // sum attention over the 8 queries: wsum[j]
  w0 += __shfl_xor(w0, 8);   w1s += __shfl_xor(w1s, 8);
  w0 += __shfl_xor(w0, 16);  w1s += __shfl_xor(w1s, 16);
  w0 += __shfl_xor(w0, 32);  w1s += __shfl_xor(w1s, 32);
  float res = 0.f;
#pragma unroll
  for (int j = 0; j < 8; ++j) {
    res += __shfl(w0, j)  * v[j];
    res += __shfl(w1s, j) * v[j + 8];
  }
  // out = w1 @ res + b1 + feature   (res broadcast by shuffle, w1T coalesced)
  float a0 = b1[o], a1 = b1[64 + o];
#pragma unroll
  for (int oo = 0; oo < 64; ++oo) {
    float rr = __shfl(res, oo);
    a0 += w1T[oo * 128 + o] * rr;
    a1 += w1T[oo * 128 + 64 + o] * rr;
  }
  const size_t obase = ((size_t)b * 128) * 4096 + n;
  out[obase + ((size_t)o << 12)]        = a0 + feature[obase + ((size_t)o << 12)];
  out[obase + ((size_t)(o + 64) << 12)] = a1 + feature[obase + ((size_t)(o + 64) << 12)];
}

// ---------------------------------------------------------------- launch
extern "C" void kernel_launch(void* const* d_in, const int* in_sizes, int n_in,
                              void* d_out, int out_size, void* d_ws, size_t ws_size,
                              hipStream_t stream) {
  const float* feature = (const float*)d_in[0];
  const float* xyz     = (const float*)d_in[1];
  const float* wq      = (const float*)d_in[2];
  const float* bq      = (const float*)d_in[3];
  const float* wk      = (const float*)d_in[4];
  const float* bk      = (const float*)d_in[5];
  const float* wv      = (const float*)d_in[6];
  const float* bv      = (const float*)d_in[7];
  const float* w1      = (const float*)d_in[8];
  const float* b1      = (const float*)d_in[9];
  float* out = (float*)d_out;

  char* ws = (char*)d_ws;
  int*   idx = (int*)ws;                       // 16384*16*4 = 1 MB
  float* uq  = (float*)(ws + (1u << 20));      // each u/c: 16384*64 floats = 4 MB
  float* cq  = uq + (1u << 20);
  float* uk  = cq + (1u << 20);
  float* ck  = uk + (1u << 20);
  float* uv  = ck + (1u << 20);
  float* cv  = uv + (1u << 20);
  float* wTq = cv + (1u << 20);
  float* wTk = wTq + 262 * 64;
  float* wTv = wTk + 262 * 64;
  float* w1T = wTv + 262 * 64;                 // 64*128

  transpose_w<<<66, 256, 0, stream>>>(wq, wk, wv, w1, wTq, wTk, wTv, w1T);
  knn_kernel<<<256, 256, 0, stream>>>(xyz, idx);
  proj_kernel<<<256, 256, 0, stream>>>(feature, xyz, wTq, wTk, wTv, bq, bk, bv,
                                       uq, cq, uk, ck, uv, cv);
  attn_kernel<<<4096, 256, 0, stream>>>(feature, idx, uq, cq, uk, ck, uv, cv, w1T, b1, out);
}

// Round 2
// 268.339 us; speedup vs baseline: 2.6354x; 2.6354x over previous
//
#include <hip/hip_runtime.h>

#define NN 4096
#define CCH 128

// ---------------------------------------------------------------- kernel 0
__global__ __launch_bounds__(256) void transpose_w(
    const float* __restrict__ wq, const float* __restrict__ wk, const float* __restrict__ wv,
    const float* __restrict__ w1,
    float* __restrict__ wTq, float* __restrict__ wTk, float* __restrict__ wTv,
    float* __restrict__ w1T) {
  int t = blockIdx.x * 256 + threadIdx.x;
  if (t < 64 * 262) {
    int o = t / 262, c = t - o * 262;
    wTq[c * 64 + o] = wq[t];
    wTk[c * 64 + o] = wk[t];
    wTv[c * 64 + o] = wv[t];
  }
  if (t < 128 * 64) {
    int r = t >> 6, c2 = t & 63;
    w1T[c2 * 128 + r] = w1[t];  // w1T[o][c]
  }
}

// ---------------------------------------------------------------- kernel 1: kNN (v2)
// 512 threads = 64 queries x 8 wave-uniform chunks of 512 candidates.
// Pass 1: distance-only top-16 via v_med3_f32 chain (1 instr/level, branch-free).
// Tree-merge chunk lists -> exact 16th distance tau per query.
// Pass 2: collect (d,m) with d<=tau via LDS atomic slots; final (d,idx) sort.
__global__ __launch_bounds__(512) void knn_kernel(const float* __restrict__ xyz,
                                                  int* __restrict__ idxout) {
  __shared__ float4 pts[NN];                      // 64 KB
  __shared__ float sdist[64 * 137];               // ~35 KB: [q]*137 + ch*17 + j
  __shared__ unsigned long long hits[64 * 32];    // 16 KB
  __shared__ int cnt[64];
  __shared__ float tauv[64];
  const int b  = blockIdx.x >> 6;
  const int n0 = (blockIdx.x & 63) << 6;
  const float* xb = xyz + (size_t)b * 3 * NN;
  for (int i = threadIdx.x; i < NN; i += 512) {
    float x = xb[i], y = xb[NN + i], z = xb[2 * NN + i];
    pts[i] = make_float4(x, y, z, x * x + y * y + z * z);
  }
  const int ql = threadIdx.x & 63;
  const int ch = threadIdx.x >> 6;  // 0..7, wave-uniform -> broadcast LDS reads
  if (threadIdx.x < 64) cnt[threadIdx.x] = 0;
  __syncthreads();
  const int q = n0 + ql;
  const float4 me = pts[q];
  float bd[16];
#pragma unroll
  for (int j = 0; j < 16; ++j) bd[j] = 3.0e38f;
  const int m0 = ch << 9, m1 = m0 + 512;
  for (int m = m0; m < m1; ++m) {
    float4 p = pts[m];
    float d = me.w + p.w - 2.0f * (me.x * p.x + me.y * p.y + me.z * p.z);
    d = (m == q) ? 3.0e38f : d;  // exclude self (ref drops the dist-0 first column)
#pragma unroll
    for (int j = 15; j >= 1; --j) bd[j] = __builtin_amdgcn_fmed3f(d, bd[j - 1], bd[j]);
    bd[0] = fminf(bd[0], d);
  }
  {
    const int base = ql * 137 + ch * 17;
#pragma unroll
    for (int j = 0; j < 16; ++j) sdist[base + j] = bd[j];
  }
  __syncthreads();
  // 3-level pairwise tree merge of sorted 16-lists (values only), in-place via reg staging
#pragma unroll
  for (int lvl = 0; lvl < 3; ++lvl) {
    const int nmerge = 4 >> lvl;  // 4,2,1
    float out[16];
    const bool active = (ch < nmerge);
    if (active) {
      const int la = ql * 137 + (2 * ch) * 17;
      const int lb = ql * 137 + (2 * ch + 1) * 17;
      int pa = 0, pb = 0;
#pragma unroll
      for (int k = 0; k < 16; ++k) {
        float va = sdist[la + pa], vb = sdist[lb + pb];
        bool takea = va <= vb;
        out[k] = takea ? va : vb;
        pa += takea ? 1 : 0;
        pb += takea ? 0 : 1;
      }
    }
    __syncthreads();
    if (active) {
      const int lo = ql * 137 + ch * 17;
#pragma unroll
      for (int k = 0; k < 16; ++k) sdist[lo + k] = out[k];
    }
    __syncthreads();
  }
  if (threadIdx.x < 64) tauv[threadIdx.x] = sdist[threadIdx.x * 137 + 15];
  __syncthreads();
  const float tau = tauv[ql];
  // pass 2: collect candidates with d <= tau (superset of top-16, incl. boundary ties)
  for (int m = m0; m < m1; ++m) {
    float4 p = pts[m];
    float d = me.w + p.w - 2.0f * (me.x * p.x + me.y * p.y + me.z * p.z);
    if (d <= tau && m != q) {
      int pos = atomicAdd(&cnt[ql], 1);
      if (pos < 32) {
        unsigned int f = __float_as_uint(d);
        f ^= (f >> 31) ? 0xFFFFFFFFu : 0x80000000u;  // monotone key incl. negatives
        hits[(ql << 5) + pos] = ((unsigned long long)f << 32) | (unsigned int)m;
      }
    }
  }
  __syncthreads();
  if (threadIdx.x < 64) {
    const int qq = threadIdx.x;
    int n = cnt[qq]; n = n > 32 ? 32 : n;
    unsigned long long kd[16];
#pragma unroll
    for (int j = 0; j < 16; ++j) kd[j] = ~0ULL;
    for (int t = 0; t < n; ++t) {
      unsigned long long key = hits[(qq << 5) + t];
#pragma unroll
      for (int j = 15; j >= 1; --j) {
        bool up   = key < kd[j - 1];
        bool here = key < kd[j];
        kd[j] = up ? kd[j - 1] : (here ? key : kd[j]);
      }
      kd[0] = key < kd[0] ? key : kd[0];
    }
    int* op = idxout + ((size_t)((b << 12) + n0 + qq)) * 16;
#pragma unroll
    for (int k = 0; k < 16; ++k) op[k] = (int)(kd[k] & 0xFFFFFFFFu);
  }
}

// ---------------------------------------------------------------- kernel 2: projections
// u[p] = W_rx*x + W_rf*f ; c[p] = (W_x*x + W_f*f + b) - u[p]   for q,k,v
__global__ __launch_bounds__(256) void proj_kernel(
    const float* __restrict__ feature, const float* __restrict__ xyz,
    const float* __restrict__ wTq, const float* __restrict__ wTk, const float* __restrict__ wTv,
    const float* __restrict__ bq, const float* __restrict__ bk, const float* __restrict__ bv,
    float* __restrict__ uq, float* __restrict__ cq,
    float* __restrict__ uk, float* __restrict__ ck,
    float* __restrict__ uv, float* __restrict__ cv) {
  __shared__ float fl[64][132];  // [point][128 fea + x,y,z + pad]
  const int b  = blockIdx.x >> 6;
  const int n0 = (blockIdx.x & 63) << 6;
  {
    const int i  = threadIdx.x & 63;
    const int c0 = threadIdx.x >> 6;
    const float* fb = feature + (size_t)b * CCH * NN + n0 + i;
    for (int cc = c0; cc < CCH; cc += 4) fl[i][cc] = fb[(size_t)cc * NN];
    if (threadIdx.x < 192) {
      const int d = threadIdx.x >> 6;  // 0..2
      fl[i][128 + d] = xyz[((size_t)b * 3 + d) * NN + n0 + i];
    }
  }
  __syncthreads();
  const int o  = threadIdx.x & 63;
  const int pg = threadIdx.x >> 6;
  const float* wt0 = wTq; const float* wt1 = wTk; const float* wt2 = wTv;
  float aU[3][16], aT[3][16];
#pragma unroll
  for (int mm = 0; mm < 3; ++mm)
#pragma unroll
    for (int s = 0; s < 16; ++s) { aU[mm][s] = 0.f; aT[mm][s] = 0.f; }
  for (int ct = 0; ct < 32; ++ct) {
    float wu[3][4], wtt[3][4];
#pragma unroll
    for (int r = 0; r < 4; ++r) {
      int c = 4 * ct + r;
      wu[0][r]  = wt0[(6 + c) * 64 + o];   wtt[0][r] = wt0[(134 + c) * 64 + o];
      wu[1][r]  = wt1[(6 + c) * 64 + o];   wtt[1][r] = wt1[(134 + c) * 64 + o];
      wu[2][r]  = wt2[(6 + c) * 64 + o];   wtt[2][r] = wt2[(134 + c) * 64 + o];
    }
#pragma unroll
    for (int s = 0; s < 16; ++s) {
      const float4 f4 = *reinterpret_cast<const float4*>(&fl[pg * 16 + s][4 * ct]);
#pragma unroll
      for (int mm = 0; mm < 3; ++mm) {
        aU[mm][s] += wu[mm][0] * f4.x + wu[mm][1] * f4.y + wu[mm][2] * f4.z + wu[mm][3] * f4.w;
        aT[mm][s] += wtt[mm][0] * f4.x + wtt[mm][1] * f4.y + wtt[mm][2] * f4.z + wtt[mm][3] * f4.w;
      }
    }
  }
  float wxu[3][3], wxt[3][3];
#pragma unroll
  for (int dd = 0; dd < 3; ++dd) {
    wxu[0][dd] = wt0[dd * 64 + o]; wxt[0][dd] = wt0[(3 + dd) * 64 + o];
    wxu[1][dd] = wt1[dd * 64 + o]; wxt[1][dd] = wt1[(3 + dd) * 64 + o];
    wxu[2][dd] = wt2[dd * 64 + o]; wxt[2][dd] = wt2[(3 + dd) * 64 + o];
  }
  const float bo0 = bq[o], bo1 = bk[o], bo2 = bv[o];
  for (int s = 0; s < 16; ++s) {
    const int p = pg * 16 + s;
    const float x = fl[p][128], y = fl[p][129], z = fl[p][130];
    const size_t gp = ((size_t)(b << 12) + n0 + p) * 64 + o;
    float uu, tt;
    uu = aU[0][s] + wxu[0][0] * x + wxu[0][1] * y + wxu[0][2] * z;
    tt = aT[0][s] + wxt[0][0] * x + wxt[0][1] * y + wxt[0][2] * z;
    uq[gp] = uu; cq[gp] = tt + bo0 - uu;
    uu = aU[1][s] + wxu[1][0] * x + wxu[1][1] * y + wxu[1][2] * z;
    tt = aT[1][s] + wxt[1][0] * x + wxt[1][1] * y + wxt[1][2] * z;
    uk[gp] = uu; ck[gp] = tt + bo1 - uu;
    uu = aU[2][s] + wxu[2][0] * x + wxu[2][1] * y + wxu[2][2] * z;
    tt = aT[2][s] + wxt[2][0] * x + wxt[2][1] * y + wxt[2][2] * z;
    uv[gp] = uu; cv[gp] = tt + bo2 - uu;
  }
}

// ---------------------------------------------------------------- kernel 3: attention + out
// One wave per point (lane = channel o of TD=64). 4 points per 256-thread block.
__global__ __launch_bounds__(256) void attn_kernel(
    const float* __restrict__ feature,
    const int* __restrict__ idx,
    const float* __restrict__ uq, const float* __restrict__ cq,
    const float* __restrict__ uk, const float* __restrict__ ck,
    const float* __restrict__ uv, const float* __restrict__ cv,
    const float* __restrict__ w1T, const float* __restrict__ b1,
    float* __restrict__ out) {
  __shared__ float kq[4][24][68];  // per wave-slot: rows 0..15 = k, 16..23 = q; stride 68
  const int slot = threadIdx.x >> 6;
  const int o    = threadIdx.x & 63;
  const int p = (blockIdx.x << 2) + slot;
  const int b = p >> 12;
  const int n = p & 4095;
  const int myidx = idx[(size_t)p * 16 + (o & 15)];
  const size_t pb = (size_t)p * 64 + o;
  const float cqo = cq[pb], cko = ck[pb], cvo = cv[pb];
  const int rowbase = (b << 12) * 64;
  float v[16];
#pragma unroll
  for (int j = 0; j < 16; ++j) {
    int nb = __shfl(myidx, j);
    int row = rowbase + nb * 64 + o;
    kq[slot][j][o] = uk[row] + cko;
    v[j] = uv[row] + cvo;
    if (j < 8) kq[slot][16 + j][o] = uq[row] + cqo;
  }
  // same-wave LDS write->read dependency: compiler inserts waitcnt, no barrier needed
  const int i  = o >> 3;   // query 0..7
  const int jj = o & 7;    // key (this lane covers jj and jj+8)
  const float* qrow = &kq[slot][16 + i][0];
  const float* k0r  = &kq[slot][jj][0];
  const float* k1r  = &kq[slot][8 + jj][0];
  float s0 = 0.f, s1 = 0.f;
#pragma unroll
  for (int t = 0; t < 16; ++t) {
    float4 q4 = *reinterpret_cast<const float4*>(qrow + 4 * t);
    float4 a4 = *reinterpret_cast<const float4*>(k0r + 4 * t);
    float4 c4 = *reinterpret_cast<const float4*>(k1r + 4 * t);
    s0 += q4.x * a4.x + q4.y * a4.y + q4.z * a4.z + q4.w * a4.w;
    s1 += q4.x * c4.x + q4.y * c4.y + q4.z * c4.z + q4.w * c4.w;
  }
  // softmax over 16 keys within each 8-lane query group
  float mx = fmaxf(s0, s1);
  mx = fmaxf(mx, __shfl_xor(mx, 1));
  mx = fmaxf(mx, __shfl_xor(mx, 2));
  mx = fmaxf(mx, __shfl_xor(mx, 4));
  float e0 = __expf(s0 - mx), e1 = __expf(s1 - mx);
  float den = e0 + e1;
  den += __shfl_xor(den, 1);
  den += __shfl_xor(den, 2);
  den += __shfl_xor(den, 4);
  const float inv = 1.0f / den;
  float w0 = e0 * inv, w1s = e1 * inv;
  // sum attention over the 8 queries: wsum[j]
  w0 += __shfl_xor(w0, 8);   w1s += __shfl_xor(w1s, 8);
  w0 += __shfl_xor(w0, 16);  w1s += __shfl_xor(w1s, 16);
  w0 += __shfl_xor(w0, 32);  w1s += __shfl_xor(w1s, 32);
  float res = 0.f;
#pragma unroll
  for (int j = 0; j < 8; ++j) {
    res += __shfl(w0, j)  * v[j];
    res += __shfl(w1s, j) * v[j + 8];
  }
  // out = w1 @ res + b1 + feature   (res broadcast by shuffle, w1T coalesced)
  float a0 = b1[o], a1 = b1[64 + o];
#pragma unroll
  for (int oo = 0; oo < 64; ++oo) {
    float rr = __shfl(res, oo);
    a0 += w1T[oo * 128 + o] * rr;
    a1 += w1T[oo * 128 + 64 + o] * rr;
  }
  const size_t obase = ((size_t)b * 128) * 4096 + n;
  out[obase + ((size_t)o << 12)]        = a0 + feature[obase + ((size_t)o << 12)];
  out[obase + ((size_t)(o + 64) << 12)] = a1 + feature[obase + ((size_t)(o + 64) << 12)];
}

// ---------------------------------------------------------------- launch
extern "C" void kernel_launch(void* const* d_in, const int* in_sizes, int n_in,
                              void* d_out, int out_size, void* d_ws, size_t ws_size,
                              hipStream_t stream) {
  const float* feature = (const float*)d_in[0];
  const float* xyz     = (const float*)d_in[1];
  const float* wq      = (const float*)d_in[2];
  const float* bq      = (const float*)d_in[3];
  const float* wk      = (const float*)d_in[4];
  const float* bk      = (const float*)d_in[5];
  const float* wv      = (const float*)d_in[6];
  const float* bv      = (const float*)d_in[7];
  const float* w1      = (const float*)d_in[8];
  const float* b1      = (const float*)d_in[9];
  float* out = (float*)d_out;

  char* ws = (char*)d_ws;
  int*   idx = (int*)ws;                       // 16384*16*4 = 1 MB
  float* uq  = (float*)(ws + (1u << 20));      // each u/c: 16384*64 floats = 4 MB
  float* cq  = uq + (1u << 20);
  float* uk  = cq + (1u << 20);
  float* ck  = uk + (1u << 20);
  float* uv  = ck + (1u << 20);
  float* cv  = uv + (1u << 20);
  float* wTq = cv + (1u << 20);
  float* wTk = wTq + 262 * 64;
  float* wTv = wTk + 262 * 64;
  float* w1T = wTv + 262 * 64;                 // 64*128

  transpose_w<<<66, 256, 0, stream>>>(wq, wk, wv, w1, wTq, wTk, wTv, w1T);
  knn_kernel<<<256, 512, 0, stream>>>(xyz, idx);
  proj_kernel<<<256, 256, 0, stream>>>(feature, xyz, wTq, wTk, wTv, bq, bk, bv,
                                       uq, cq, uk, ck, uv, cv);
  attn_kernel<<<4096, 256, 0, stream>>>(feature, idx, uq, cq, uk, ck, uv, cv, w1T, b1, out);
}

// Round 3
// 246.461 us; speedup vs baseline: 2.8693x; 1.0888x over previous
//
#include <hip/hip_runtime.h>

#define NN 4096
#define CCH 128

// ---------------------------------------------------------------- kernel 0: weight packing
__global__ __launch_bounds__(256) void transpose_w(
    const float* __restrict__ wq, const float* __restrict__ wk, const float* __restrict__ wv,
    const float* __restrict__ w1,
    float* __restrict__ wTq, float* __restrict__ wTk, float* __restrict__ wTv,
    float* __restrict__ w1T, float* __restrict__ wPack) {
  int t = blockIdx.x * 256 + threadIdx.x;
  if (t < 64 * 262) {
    int o = t / 262, c = t - o * 262;
    wTq[c * 64 + o] = wq[t];
    wTk[c * 64 + o] = wk[t];
    wTv[c * 64 + o] = wv[t];
  }
  if (t < 128 * 64) {
    int r = t >> 6, c2 = t & 63;
    w1T[c2 * 128 + r] = w1[t];  // w1T[o][c]
  }
  if (t < 49152) {  // wPack[ct][mh][o][r]: mh = mat*2 + half; half0 rows 6+, half1 rows 134+
    int r = t & 3, o = (t >> 2) & 63;
    int g = t >> 8;            // ct*6 + mh
    int ct = g / 6, mh = g - ct * 6;
    int m = mh >> 1, h = mh & 1;
    const float* wsrc = (m == 0) ? wq : ((m == 1) ? wk : wv);
    wPack[t] = wsrc[o * 262 + (h ? 134 : 6) + 4 * ct + r];
  }
}

// ---------------------------------------------------------------- kernel 1: kNN (v3)
// 512 threads = 64 queries x 8 wave-uniform chunks of 512 candidates.
// Pass 1 (unroll 8, batched ds_read_b128): per-chunk sorted top-16 dists via med3 chain.
// Tree-merge -> exact 16th distance tau. Pass 2: collect d<=tau; exact (d,idx) sort.
__global__ __launch_bounds__(512) void knn_kernel(const float* __restrict__ xyz,
                                                  int* __restrict__ idxout) {
  __shared__ float4 pts[NN];                    // 64 KB
  __shared__ float sdist[8 * 16 * 64];          // 32 KB, [ch][j][q] lane-consecutive
  __shared__ unsigned long long hits[32 * 64];  // 16 KB, [pos][q] lane-consecutive
  __shared__ int cnt[64];
  const int b  = blockIdx.x >> 6;
  const int n0 = (blockIdx.x & 63) << 6;
  const float* xb = xyz + (size_t)b * 3 * NN;
  for (int i = threadIdx.x; i < NN; i += 512) {
    float x = xb[i], y = xb[NN + i], z = xb[2 * NN + i];
    pts[i] = make_float4(x, y, z, x * x + y * y + z * z);
  }
  const int ql = threadIdx.x & 63;
  const int ch = threadIdx.x >> 6;  // wave-uniform
  if (threadIdx.x < 64) cnt[threadIdx.x] = 0;
  __syncthreads();
  const int q = n0 + ql;
  const float4 me = pts[q];
  float bd[16];
#pragma unroll
  for (int j = 0; j < 16; ++j) bd[j] = 3.0e38f;
  const int m0 = ch << 9, m1 = m0 + 512;
  for (int mb = m0; mb < m1; mb += 8) {
    float4 P[8];
#pragma unroll
    for (int u = 0; u < 8; ++u) P[u] = pts[mb + u];
#pragma unroll
    for (int u = 0; u < 8; ++u) {
      float d = me.w + P[u].w - 2.0f * (me.x * P[u].x + me.y * P[u].y + me.z * P[u].z);
      d = (mb + u == q) ? 3.0e38f : d;  // exclude self
#pragma unroll
      for (int j = 15; j >= 1; --j) bd[j] = __builtin_amdgcn_fmed3f(d, bd[j - 1], bd[j]);
      bd[0] = fminf(bd[0], d);
    }
  }
#pragma unroll
  for (int j = 0; j < 16; ++j) sdist[(ch * 16 + j) * 64 + ql] = bd[j];
  __syncthreads();
#pragma unroll
  for (int lvl = 0; lvl < 3; ++lvl) {
    const int nmerge = 4 >> lvl;
    float outv[16];
    const bool active = (ch < nmerge);
    if (active) {
      const float* A  = &sdist[((2 * ch) * 16) * 64 + ql];
      const float* Bp = &sdist[((2 * ch + 1) * 16) * 64 + ql];
      int pa = 0, pb = 0;
#pragma unroll
      for (int k = 0; k < 16; ++k) {
        float va = A[pa * 64], vb = Bp[pb * 64];
        bool takea = va <= vb;
        outv[k] = takea ? va : vb;
        pa += takea ? 1 : 0;
        pb += takea ? 0 : 1;
      }
    }
    __syncthreads();
    if (active) {
#pragma unroll
      for (int k = 0; k < 16; ++k) sdist[(ch * 16 + k) * 64 + ql] = outv[k];
    }
    __syncthreads();
  }
  const float tau = sdist[15 * 64 + ql];
  // pass 2: collect all candidates with d <= tau (>=16 incl. ties; buffer 32)
  for (int mb = m0; mb < m1; mb += 8) {
    float4 P[8];
#pragma unroll
    for (int u = 0; u < 8; ++u) P[u] = pts[mb + u];
#pragma unroll
    for (int u = 0; u < 8; ++u) {
      float d = me.w + P[u].w - 2.0f * (me.x * P[u].x + me.y * P[u].y + me.z * P[u].z);
      if (d <= tau && (mb + u) != q) {
        int pos = atomicAdd(&cnt[ql], 1);
        if (pos < 32) {
          unsigned int f = __float_as_uint(d);
          f ^= (f >> 31) ? 0xFFFFFFFFu : 0x80000000u;  // monotone key
          hits[pos * 64 + ql] = ((unsigned long long)f << 32) | (unsigned int)(mb + u);
        }
      }
    }
  }
  __syncthreads();
  if (threadIdx.x < 64) {
    const int qq = threadIdx.x;
    int n = cnt[qq]; n = n > 32 ? 32 : n;
    unsigned long long kd[16];
#pragma unroll
    for (int j = 0; j < 16; ++j) kd[j] = ~0ULL;
    for (int t = 0; t < n; ++t) {
      unsigned long long key = hits[t * 64 + qq];  // lane-consecutive: conflict-free
#pragma unroll
      for (int j = 15; j >= 1; --j) {
        bool up   = key < kd[j - 1];
        bool here = key < kd[j];
        kd[j] = up ? kd[j - 1] : (here ? key : kd[j]);
      }
      kd[0] = key < kd[0] ? key : kd[0];
    }
    int* op = idxout + ((size_t)((b << 12) + n0 + qq)) * 16;
#pragma unroll
    for (int k = 0; k < 16; ++k) op[k] = (int)(kd[k] & 0xFFFFFFFFu);
  }
}

// ---------------------------------------------------------------- kernel 2: projections (v2)
// 1024 blocks x 256 thr; 16 points/block; lane=o, pg=t>>6 handles 4 points.
// Weights via wPack: 6 coalesced dwordx4 per K-tile of 4 channels.
__global__ __launch_bounds__(256) void proj_kernel(
    const float* __restrict__ feature, const float* __restrict__ xyz,
    const float* __restrict__ wTq, const float* __restrict__ wTk, const float* __restrict__ wTv,
    const float* __restrict__ wPack,
    const float* __restrict__ bq, const float* __restrict__ bk, const float* __restrict__ bv,
    float* __restrict__ uq, float* __restrict__ cq,
    float* __restrict__ uk, float* __restrict__ ck,
    float* __restrict__ uv, float* __restrict__ cv) {
  __shared__ float fl[16][132];  // [point][128 fea + x,y,z + pad]
  const int p0 = blockIdx.x << 4;  // global point base
  const int b  = p0 >> 12;
  const int n0 = p0 & 4095;
  {
    const int i  = threadIdx.x & 15;
    const int c0 = threadIdx.x >> 4;  // 0..15
    const float* fb = feature + (size_t)b * CCH * NN + n0 + i;
    for (int cc = c0; cc < CCH; cc += 16) fl[i][cc] = fb[(size_t)cc * NN];
    if (threadIdx.x < 48) {
      const int d = threadIdx.x >> 4;  // 0..2
      fl[i][128 + d] = xyz[((size_t)b * 3 + d) * NN + n0 + i];
    }
  }
  __syncthreads();
  const int o  = threadIdx.x & 63;
  const int pg = threadIdx.x >> 6;  // 0..3 -> 4 points each
  const float4* wp = reinterpret_cast<const float4*>(wPack);
  float aU[3][4], aT[3][4];
#pragma unroll
  for (int mm = 0; mm < 3; ++mm)
#pragma unroll
    for (int s = 0; s < 4; ++s) { aU[mm][s] = 0.f; aT[mm][s] = 0.f; }
  for (int ct = 0; ct < 32; ++ct) {
    float4 w4[6];
#pragma unroll
    for (int mh = 0; mh < 6; ++mh) w4[mh] = wp[(ct * 6 + mh) * 64 + o];
#pragma unroll
    for (int s = 0; s < 4; ++s) {
      const float4 f4 = *reinterpret_cast<const float4*>(&fl[pg * 4 + s][4 * ct]);
#pragma unroll
      for (int mm = 0; mm < 3; ++mm) {
        aU[mm][s] += w4[2 * mm].x * f4.x + w4[2 * mm].y * f4.y + w4[2 * mm].z * f4.z + w4[2 * mm].w * f4.w;
        aT[mm][s] += w4[2 * mm + 1].x * f4.x + w4[2 * mm + 1].y * f4.y + w4[2 * mm + 1].z * f4.z + w4[2 * mm + 1].w * f4.w;
      }
    }
  }
  float wxu[3][3], wxt[3][3];
#pragma unroll
  for (int dd = 0; dd < 3; ++dd) {
    wxu[0][dd] = wTq[dd * 64 + o]; wxt[0][dd] = wTq[(3 + dd) * 64 + o];
    wxu[1][dd] = wTk[dd * 64 + o]; wxt[1][dd] = wTk[(3 + dd) * 64 + o];
    wxu[2][dd] = wTv[dd * 64 + o]; wxt[2][dd] = wTv[(3 + dd) * 64 + o];
  }
  const float bo0 = bq[o], bo1 = bk[o], bo2 = bv[o];
#pragma unroll
  for (int s = 0; s < 4; ++s) {
    const int p = pg * 4 + s;
    const float x = fl[p][128], y = fl[p][129], z = fl[p][130];
    const size_t gp = ((size_t)(p0 + p)) * 64 + o;
    float uu, tt;
    uu = aU[0][s] + wxu[0][0] * x + wxu[0][1] * y + wxu[0][2] * z;
    tt = aT[0][s] + wxt[0][0] * x + wxt[0][1] * y + wxt[0][2] * z;
    uq[gp] = uu; cq[gp] = tt + bo0 - uu;
    uu = aU[1][s] + wxu[1][0] * x + wxu[1][1] * y + wxu[1][2] * z;
    tt = aT[1][s] + wxt[1][0] * x + wxt[1][1] * y + wxt[1][2] * z;
    uk[gp] = uu; ck[gp] = tt + bo1 - uu;
    uu = aU[2][s] + wxu[2][0] * x + wxu[2][1] * y + wxu[2][2] * z;
    tt = aT[2][s] + wxt[2][0] * x + wxt[2][1] * y + wxt[2][2] * z;
    uv[gp] = uu; cv[gp] = tt + bo2 - uu;
  }
}

// ---------------------------------------------------------------- kernel 3: attention core
// One wave per point; writes res[p][64] coalesced (epilogue split off).
__global__ __launch_bounds__(256) void attn_core(
    const int* __restrict__ idx,
    const float* __restrict__ uq, const float* __restrict__ cq,
    const float* __restrict__ uk, const float* __restrict__ ck,
    const float* __restrict__ uv, const float* __restrict__ cv,
    float* __restrict__ res_ws) {
  __shared__ float kq[4][24][68];
  const int slot = threadIdx.x >> 6;
  const int o    = threadIdx.x & 63;
  const int p = (blockIdx.x << 2) + slot;
  const int b = p >> 12;
  const int myidx = idx[(size_t)p * 16 + (o & 15)];
  const size_t pb = (size_t)p * 64 + o;
  const float cqo = cq[pb], cko = ck[pb], cvo = cv[pb];
  const int rowbase = (b << 12) * 64;
  float v[16];
#pragma unroll
  for (int j = 0; j < 16; ++j) {
    int nb = __shfl(myidx, j);
    int row = rowbase + nb * 64 + o;
    kq[slot][j][o] = uk[row] + cko;
    v[j] = uv[row] + cvo;
    if (j < 8) kq[slot][16 + j][o] = uq[row] + cqo;
  }
  const int i  = o >> 3;
  const int jj = o & 7;
  const float* qrow = &kq[slot][16 + i][0];
  const float* k0r  = &kq[slot][jj][0];
  const float* k1r  = &kq[slot][8 + jj][0];
  float s0 = 0.f, s1 = 0.f;
#pragma unroll
  for (int t = 0; t < 16; ++t) {
    float4 q4 = *reinterpret_cast<const float4*>(qrow + 4 * t);
    float4 a4 = *reinterpret_cast<const float4*>(k0r + 4 * t);
    float4 c4 = *reinterpret_cast<const float4*>(k1r + 4 * t);
    s0 += q4.x * a4.x + q4.y * a4.y + q4.z * a4.z + q4.w * a4.w;
    s1 += q4.x * c4.x + q4.y * c4.y + q4.z * c4.z + q4.w * c4.w;
  }
  float mx = fmaxf(s0, s1);
  mx = fmaxf(mx, __shfl_xor(mx, 1));
  mx = fmaxf(mx, __shfl_xor(mx, 2));
  mx = fmaxf(mx, __shfl_xor(mx, 4));
  float e0 = __expf(s0 - mx), e1 = __expf(s1 - mx);
  float den = e0 + e1;
  den += __shfl_xor(den, 1);
  den += __shfl_xor(den, 2);
  den += __shfl_xor(den, 4);
  const float inv = 1.0f / den;
  float w0 = e0 * inv, w1s = e1 * inv;
  w0 += __shfl_xor(w0, 8);   w1s += __shfl_xor(w1s, 8);
  w0 += __shfl_xor(w0, 16);  w1s += __shfl_xor(w1s, 16);
  w0 += __shfl_xor(w0, 32);  w1s += __shfl_xor(w1s, 32);
  float res = 0.f;
#pragma unroll
  for (int j = 0; j < 8; ++j) {
    res += __shfl(w0, j)  * v[j];
    res += __shfl(w1s, j) * v[j + 8];
  }
  res_ws[pb] = res;  // coalesced
}

// ---------------------------------------------------------------- kernel 4: output GEMM epilogue
// out[b][c][n] = sum_o w1[c][o]*res[p][o] + b1[c] + feature[b][c][n]; lane = n (coalesced).
__global__ __launch_bounds__(256) void out_kernel(
    const float* __restrict__ feature, const float* __restrict__ res,
    const float* __restrict__ w1T, const float* __restrict__ b1,
    float* __restrict__ out) {
  __shared__ float rT[64][66];
  const int p0 = blockIdx.x << 6;
  const int b  = p0 >> 12;
  const int n0 = p0 & 4095;
  {
    const int o = threadIdx.x & 63;
    for (int pp = threadIdx.x >> 6; pp < 64; pp += 4)
      rT[o][pp] = res[(size_t)(p0 + pp) * 64 + o];  // coalesced read, 2-way LDS write
  }
  __syncthreads();
  const int n = threadIdx.x & 63;
  const int c0 = (threadIdx.x >> 6) * 32;
  float acc[32];
#pragma unroll
  for (int cc = 0; cc < 32; ++cc) acc[cc] = b1[c0 + cc];
  for (int o = 0; o < 64; ++o) {
    const float rr = rT[o][n];
    const float* wrow = &w1T[o * 128 + c0];  // uniform -> scalar loads
#pragma unroll
    for (int cc = 0; cc < 32; ++cc) acc[cc] += wrow[cc] * rr;
  }
#pragma unroll
  for (int cc = 0; cc < 32; ++cc) {
    const size_t gi = ((size_t)(b * 128 + c0 + cc) << 12) + n0 + n;
    out[gi] = acc[cc] + feature[gi];
  }
}

// ---------------------------------------------------------------- launch
extern "C" void kernel_launch(void* const* d_in, const int* in_sizes, int n_in,
                              void* d_out, int out_size, void* d_ws, size_t ws_size,
                              hipStream_t stream) {
  const float* feature = (const float*)d_in[0];
  const float* xyz     = (const float*)d_in[1];
  const float* wq      = (const float*)d_in[2];
  const float* bq      = (const float*)d_in[3];
  const float* wk      = (const float*)d_in[4];
  const float* bk      = (const float*)d_in[5];
  const float* wv      = (const float*)d_in[6];
  const float* bv      = (const float*)d_in[7];
  const float* w1      = (const float*)d_in[8];
  const float* b1      = (const float*)d_in[9];
  float* out = (float*)d_out;

  char* ws = (char*)d_ws;
  int*   idx = (int*)ws;                    // 1 MB
  float* uq  = (float*)(ws + (1u << 20));   // 4 MB each
  float* cq  = uq + (1u << 20);
  float* uk  = cq + (1u << 20);
  float* ck  = uk + (1u << 20);
  float* uv  = ck + (1u << 20);
  float* cv  = uv + (1u << 20);
  float* res = cv + (1u << 20);             // 4 MB
  float* wTq = res + (1u << 20);
  float* wTk = wTq + 262 * 64;
  float* wTv = wTk + 262 * 64;
  float* w1T = wTv + 262 * 64;              // 64*128
  float* wPk = w1T + 128 * 64;              // 49152 floats

  transpose_w<<<192, 256, 0, stream>>>(wq, wk, wv, w1, wTq, wTk, wTv, w1T, wPk);
  knn_kernel<<<256, 512, 0, stream>>>(xyz, idx);
  proj_kernel<<<1024, 256, 0, stream>>>(feature, xyz, wTq, wTk, wTv, wPk, bq, bk, bv,
                                        uq, cq, uk, ck, uv, cv);
  attn_core<<<4096, 256, 0, stream>>>(idx, uq, cq, uk, ck, uv, cv, res);
  out_kernel<<<256, 256, 0, stream>>>(feature, res, w1T, b1, out);
}

// Round 4
// 230.753 us; speedup vs baseline: 3.0647x; 1.0681x over previous
//
#include <hip/hip_runtime.h>

#define NN 4096
#define CCH 128

// ---------------------------------------------------------------- kernel 0: weight packing
__global__ __launch_bounds__(256) void transpose_w(
    const float* __restrict__ wq, const float* __restrict__ wk, const float* __restrict__ wv,
    const float* __restrict__ w1,
    float* __restrict__ wTq, float* __restrict__ wTk, float* __restrict__ wTv,
    float* __restrict__ w1T, float* __restrict__ wPack) {
  int t = blockIdx.x * 256 + threadIdx.x;
  if (t < 64 * 262) {
    int o = t / 262, c = t - o * 262;
    wTq[c * 64 + o] = wq[t];
    wTk[c * 64 + o] = wk[t];
    wTv[c * 64 + o] = wv[t];
  }
  if (t < 128 * 64) {
    int r = t >> 6, c2 = t & 63;
    w1T[c2 * 128 + r] = w1[t];  // w1T[o][c]
  }
  if (t < 49152) {  // wPack[ct][mh][o][r]: mh = mat*2 + half; half0 rows 6+, half1 rows 134+
    int r = t & 3, o = (t >> 2) & 63;
    int g = t >> 8;            // ct*6 + mh
    int ct = g / 6, mh = g - ct * 6;
    int m = mh >> 1, h = mh & 1;
    const float* wsrc = (m == 0) ? wq : ((m == 1) ? wk : wv);
    wPack[t] = wsrc[o * 262 + (h ? 134 : 6) + 4 * ct + r];
  }
}

// ---------------------------------------------------------------- kernel 1: kNN (v4)
// 1024 threads = 64 queries x 16 wave-uniform chunks of 256 candidates (4 waves/SIMD).
// Pass 1: branchless med3-chain top-16 dists per chunk. 4-level tree merge -> exact tau.
// Pass 2: collect d<=tau; exact (key,idx) insertion sort reproduces top_k order.
__global__ __launch_bounds__(1024, 4) void knn_kernel(const float* __restrict__ xyz,
                                                      int* __restrict__ idxout) {
  __shared__ float4 pts[NN];                    // 64 KB
  __shared__ float sdist[16 * 16 * 64];         // 64 KB, [ch][j][q] lane-consecutive
  __shared__ unsigned long long hits[32 * 64];  // 16 KB, [pos][q] lane-consecutive
  __shared__ int cnt[64];
  const int b  = blockIdx.x >> 6;
  const int n0 = (blockIdx.x & 63) << 6;
  const float* xb = xyz + (size_t)b * 3 * NN;
  for (int i = threadIdx.x; i < NN; i += 1024) {
    float x = xb[i], y = xb[NN + i], z = xb[2 * NN + i];
    pts[i] = make_float4(x, y, z, x * x + y * y + z * z);
  }
  const int ql = threadIdx.x & 63;
  const int ch = threadIdx.x >> 6;  // 0..15, wave-uniform
  if (threadIdx.x < 64) cnt[threadIdx.x] = 0;
  __syncthreads();
  const int q = n0 + ql;
  const float4 me = pts[q];
  float bd[16];
#pragma unroll
  for (int j = 0; j < 16; ++j) bd[j] = 3.0e38f;
  const int m0 = ch << 8, m1 = m0 + 256;
  for (int mb = m0; mb < m1; mb += 8) {
    float4 P[8];
#pragma unroll
    for (int u = 0; u < 8; ++u) P[u] = pts[mb + u];
#pragma unroll
    for (int u = 0; u < 8; ++u) {
      float d = me.w + P[u].w - 2.0f * (me.x * P[u].x + me.y * P[u].y + me.z * P[u].z);
      d = (mb + u == q) ? 3.0e38f : d;  // exclude self
#pragma unroll
      for (int j = 15; j >= 1; --j) bd[j] = __builtin_amdgcn_fmed3f(d, bd[j - 1], bd[j]);
      bd[0] = fminf(bd[0], d);
    }
  }
#pragma unroll
  for (int j = 0; j < 16; ++j) sdist[(ch * 16 + j) * 64 + ql] = bd[j];
  __syncthreads();
#pragma unroll
  for (int lvl = 0; lvl < 4; ++lvl) {
    const int nmerge = 8 >> lvl;  // 8,4,2,1
    float outv[16];
    const bool active = (ch < nmerge);
    if (active) {
      const float* A  = &sdist[((2 * ch) * 16) * 64 + ql];
      const float* Bp = &sdist[((2 * ch + 1) * 16) * 64 + ql];
      int pa = 0, pb = 0;
#pragma unroll
      for (int k = 0; k < 16; ++k) {
        float va = A[pa * 64], vb = Bp[pb * 64];
        bool takea = va <= vb;
        outv[k] = takea ? va : vb;
        pa += takea ? 1 : 0;
        pb += takea ? 0 : 1;
      }
    }
    __syncthreads();
    if (active) {
#pragma unroll
      for (int k = 0; k < 16; ++k) sdist[(ch * 16 + k) * 64 + ql] = outv[k];
    }
    __syncthreads();
  }
  const float tau = sdist[15 * 64 + ql];
  // pass 2: collect all candidates with d <= tau (>=16 incl. ties; buffer 32)
  for (int mb = m0; mb < m1; mb += 8) {
    float4 P[8];
#pragma unroll
    for (int u = 0; u < 8; ++u) P[u] = pts[mb + u];
#pragma unroll
    for (int u = 0; u < 8; ++u) {
      float d = me.w + P[u].w - 2.0f * (me.x * P[u].x + me.y * P[u].y + me.z * P[u].z);
      if (d <= tau && (mb + u) != q) {
        int pos = atomicAdd(&cnt[ql], 1);
        if (pos < 32) {
          unsigned int f = __float_as_uint(d);
          f ^= (f >> 31) ? 0xFFFFFFFFu : 0x80000000u;  // monotone key
          hits[pos * 64 + ql] = ((unsigned long long)f << 32) | (unsigned int)(mb + u);
        }
      }
    }
  }
  __syncthreads();
  if (threadIdx.x < 64) {
    const int qq = threadIdx.x;
    int n = cnt[qq]; n = n > 32 ? 32 : n;
    unsigned long long kd[16];
#pragma unroll
    for (int j = 0; j < 16; ++j) kd[j] = ~0ULL;
    for (int t = 0; t < n; ++t) {
      unsigned long long key = hits[t * 64 + qq];  // lane-consecutive: conflict-free
#pragma unroll
      for (int j = 15; j >= 1; --j) {
        bool up   = key < kd[j - 1];
        bool here = key < kd[j];
        kd[j] = up ? kd[j - 1] : (here ? key : kd[j]);
      }
      kd[0] = key < kd[0] ? key : kd[0];
    }
    int* op = idxout + ((size_t)((b << 12) + n0 + qq)) * 16;
#pragma unroll
    for (int k = 0; k < 16; ++k) op[k] = (int)(kd[k] & 0xFFFFFFFFu);
  }
}

// ---------------------------------------------------------------- kernel 2: projections (v3)
// 512 blocks x 256 thr; 32 points/block; lane=o, pg=t>>6 handles 8 points.
// 6 coalesced dwordx4 weight loads per K-tile amortized over 192 FMAs.
__global__ __launch_bounds__(256, 4) void proj_kernel(
    const float* __restrict__ feature, const float* __restrict__ xyz,
    const float* __restrict__ wTq, const float* __restrict__ wTk, const float* __restrict__ wTv,
    const float* __restrict__ wPack,
    const float* __restrict__ bq, const float* __restrict__ bk, const float* __restrict__ bv,
    float* __restrict__ uq, float* __restrict__ cq,
    float* __restrict__ uk, float* __restrict__ ck,
    float* __restrict__ uv, float* __restrict__ cv) {
  __shared__ float fl[32][132];  // [point][128 fea + x,y,z + pad]
  const int p0 = blockIdx.x << 5;  // global point base (32 per block)
  const int b  = p0 >> 12;
  const int n0 = p0 & 4095;
  {
    const int i  = threadIdx.x & 31;
    const int c0 = threadIdx.x >> 5;  // 0..7
    const float* fb = feature + (size_t)b * CCH * NN + n0 + i;
    for (int cc = c0; cc < CCH; cc += 8) fl[i][cc] = fb[(size_t)cc * NN];
    if (threadIdx.x < 96) {
      const int d = threadIdx.x >> 5;  // 0..2
      fl[i][128 + d] = xyz[((size_t)b * 3 + d) * NN + n0 + i];
    }
  }
  __syncthreads();
  const int o  = threadIdx.x & 63;
  const int pg = threadIdx.x >> 6;  // 0..3 -> 8 points each
  const float4* wp = reinterpret_cast<const float4*>(wPack);
  float aU[3][8], aT[3][8];
#pragma unroll
  for (int mm = 0; mm < 3; ++mm)
#pragma unroll
    for (int s = 0; s < 8; ++s) { aU[mm][s] = 0.f; aT[mm][s] = 0.f; }
  for (int ct = 0; ct < 32; ++ct) {
    float4 w4[6];
#pragma unroll
    for (int mh = 0; mh < 6; ++mh) w4[mh] = wp[(ct * 6 + mh) * 64 + o];
#pragma unroll
    for (int s = 0; s < 8; ++s) {
      const float4 f4 = *reinterpret_cast<const float4*>(&fl[pg * 8 + s][4 * ct]);
#pragma unroll
      for (int mm = 0; mm < 3; ++mm) {
        aU[mm][s] += w4[2 * mm].x * f4.x + w4[2 * mm].y * f4.y + w4[2 * mm].z * f4.z + w4[2 * mm].w * f4.w;
        aT[mm][s] += w4[2 * mm + 1].x * f4.x + w4[2 * mm + 1].y * f4.y + w4[2 * mm + 1].z * f4.z + w4[2 * mm + 1].w * f4.w;
      }
    }
  }
  float wxu[3][3], wxt[3][3];
#pragma unroll
  for (int dd = 0; dd < 3; ++dd) {
    wxu[0][dd] = wTq[dd * 64 + o]; wxt[0][dd] = wTq[(3 + dd) * 64 + o];
    wxu[1][dd] = wTk[dd * 64 + o]; wxt[1][dd] = wTk[(3 + dd) * 64 + o];
    wxu[2][dd] = wTv[dd * 64 + o]; wxt[2][dd] = wTv[(3 + dd) * 64 + o];
  }
  const float bo0 = bq[o], bo1 = bk[o], bo2 = bv[o];
#pragma unroll
  for (int s = 0; s < 8; ++s) {
    const int p = pg * 8 + s;
    const float x = fl[p][128], y = fl[p][129], z = fl[p][130];
    const size_t gp = ((size_t)(p0 + p)) * 64 + o;
    float uu, tt;
    uu = aU[0][s] + wxu[0][0] * x + wxu[0][1] * y + wxu[0][2] * z;
    tt = aT[0][s] + wxt[0][0] * x + wxt[0][1] * y + wxt[0][2] * z;
    uq[gp] = uu; cq[gp] = tt + bo0 - uu;
    uu = aU[1][s] + wxu[1][0] * x + wxu[1][1] * y + wxu[1][2] * z;
    tt = aT[1][s] + wxt[1][0] * x + wxt[1][1] * y + wxt[1][2] * z;
    uk[gp] = uu; ck[gp] = tt + bo1 - uu;
    uu = aU[2][s] + wxu[2][0] * x + wxu[2][1] * y + wxu[2][2] * z;
    tt = aT[2][s] + wxt[2][0] * x + wxt[2][1] * y + wxt[2][2] * z;
    uv[gp] = uu; cv[gp] = tt + bo2 - uu;
  }
}

// ---------------------------------------------------------------- kernel 3: attention core
// One wave per point; writes res[p][64] coalesced (epilogue split off).
__global__ __launch_bounds__(256) void attn_core(
    const int* __restrict__ idx,
    const float* __restrict__ uq, const float* __restrict__ cq,
    const float* __restrict__ uk, const float* __restrict__ ck,
    const float* __restrict__ uv, const float* __restrict__ cv,
    float* __restrict__ res_ws) {
  __shared__ float kq[4][24][68];
  const int slot = threadIdx.x >> 6;
  const int o    = threadIdx.x & 63;
  const int p = (blockIdx.x << 2) + slot;
  const int b = p >> 12;
  const int myidx = idx[(size_t)p * 16 + (o & 15)];
  const size_t pb = (size_t)p * 64 + o;
  const float cqo = cq[pb], cko = ck[pb], cvo = cv[pb];
  const int rowbase = (b << 12) * 64;
  float v[16];
#pragma unroll
  for (int j = 0; j < 16; ++j) {
    int nb = __shfl(myidx, j);
    int row = rowbase + nb * 64 + o;
    kq[slot][j][o] = uk[row] + cko;
    v[j] = uv[row] + cvo;
    if (j < 8) kq[slot][16 + j][o] = uq[row] + cqo;
  }
  const int i  = o >> 3;
  const int jj = o & 7;
  const float* qrow = &kq[slot][16 + i][0];
  const float* k0r  = &kq[slot][jj][0];
  const float* k1r  = &kq[slot][8 + jj][0];
  float s0 = 0.f, s1 = 0.f;
#pragma unroll
  for (int t = 0; t < 16; ++t) {
    float4 q4 = *reinterpret_cast<const float4*>(qrow + 4 * t);
    float4 a4 = *reinterpret_cast<const float4*>(k0r + 4 * t);
    float4 c4 = *reinterpret_cast<const float4*>(k1r + 4 * t);
    s0 += q4.x * a4.x + q4.y * a4.y + q4.z * a4.z + q4.w * a4.w;
    s1 += q4.x * c4.x + q4.y * c4.y + q4.z * c4.z + q4.w * c4.w;
  }
  float mx = fmaxf(s0, s1);
  mx = fmaxf(mx, __shfl_xor(mx, 1));
  mx = fmaxf(mx, __shfl_xor(mx, 2));
  mx = fmaxf(mx, __shfl_xor(mx, 4));
  float e0 = __expf(s0 - mx), e1 = __expf(s1 - mx);
  float den = e0 + e1;
  den += __shfl_xor(den, 1);
  den += __shfl_xor(den, 2);
  den += __shfl_xor(den, 4);
  const float inv = 1.0f / den;
  float w0 = e0 * inv, w1s = e1 * inv;
  w0 += __shfl_xor(w0, 8);   w1s += __shfl_xor(w1s, 8);
  w0 += __shfl_xor(w0, 16);  w1s += __shfl_xor(w1s, 16);
  w0 += __shfl_xor(w0, 32);  w1s += __shfl_xor(w1s, 32);
  float res = 0.f;
#pragma unroll
  for (int j = 0; j < 8; ++j) {
    res += __shfl(w0, j)  * v[j];
    res += __shfl(w1s, j) * v[j + 8];
  }
  res_ws[pb] = res;  // coalesced
}

// ---------------------------------------------------------------- kernel 4: output GEMM epilogue
// out[b][c][n] = sum_o w1[c][o]*res[p][o] + b1[c] + feature[b][c][n]; lane = n (coalesced).
__global__ __launch_bounds__(256) void out_kernel(
    const float* __restrict__ feature, const float* __restrict__ res,
    const float* __restrict__ w1T, const float* __restrict__ b1,
    float* __restrict__ out) {
  __shared__ float rT[64][66];
  const int p0 = blockIdx.x << 6;
  const int b  = p0 >> 12;
  const int n0 = p0 & 4095;
  {
    const int o = threadIdx.x & 63;
    for (int pp = threadIdx.x >> 6; pp < 64; pp += 4)
      rT[o][pp] = res[(size_t)(p0 + pp) * 64 + o];  // coalesced read
  }
  __syncthreads();
  const int n = threadIdx.x & 63;
  const int c0 = (threadIdx.x >> 6) * 32;
  float acc[32];
#pragma unroll
  for (int cc = 0; cc < 32; ++cc) acc[cc] = b1[c0 + cc];
  for (int o = 0; o < 64; ++o) {
    const float rr = rT[o][n];
    const float* wrow = &w1T[o * 128 + c0];  // uniform -> scalar loads
#pragma unroll
    for (int cc = 0; cc < 32; ++cc) acc[cc] += wrow[cc] * rr;
  }
#pragma unroll
  for (int cc = 0; cc < 32; ++cc) {
    const size_t gi = ((size_t)(b * 128 + c0 + cc) << 12) + n0 + n;
    out[gi] = acc[cc] + feature[gi];
  }
}

// ---------------------------------------------------------------- launch
extern "C" void kernel_launch(void* const* d_in, const int* in_sizes, int n_in,
                              void* d_out, int out_size, void* d_ws, size_t ws_size,
                              hipStream_t stream) {
  const float* feature = (const float*)d_in[0];
  const float* xyz     = (const float*)d_in[1];
  const float* wq      = (const float*)d_in[2];
  const float* bq      = (const float*)d_in[3];
  const float* wk      = (const float*)d_in[4];
  const float* bk      = (const float*)d_in[5];
  const float* wv      = (const float*)d_in[6];
  const float* bv      = (const float*)d_in[7];
  const float* w1      = (const float*)d_in[8];
  const float* b1      = (const float*)d_in[9];
  float* out = (float*)d_out;

  char* ws = (char*)d_ws;
  int*   idx = (int*)ws;                    // 1 MB
  float* uq  = (float*)(ws + (1u << 20));   // 4 MB each
  float* cq  = uq + (1u << 20);
  float* uk  = cq + (1u << 20);
  float* ck  = uk + (1u << 20);
  float* uv  = ck + (1u << 20);
  float* cv  = uv + (1u << 20);
  float* res = cv + (1u << 20);             // 4 MB
  float* wTq = res + (1u << 20);
  float* wTk = wTq + 262 * 64;
  float* wTv = wTk + 262 * 64;
  float* w1T = wTv + 262 * 64;              // 64*128
  float* wPk = w1T + 128 * 64;              // 49152 floats

  transpose_w<<<192, 256, 0, stream>>>(wq, wk, wv, w1, wTq, wTk, wTv, w1T, wPk);
  knn_kernel<<<256, 1024, 0, stream>>>(xyz, idx);
  proj_kernel<<<512, 256, 0, stream>>>(feature, xyz, wTq, wTk, wTv, wPk, bq, bk, bv,
                                       uq, cq, uk, ck, uv, cv);
  attn_core<<<4096, 256, 0, stream>>>(idx, uq, cq, uk, ck, uv, cv, res);
  out_kernel<<<256, 256, 0, stream>>>(feature, res, w1T, b1, out);
}